// Round 1
// baseline (13292.027 us; speedup 1.0000x reference)
//
#include <hip/hip_runtime.h>
#include <hip/hip_cooperative_groups.h>

namespace cg = cooperative_groups;

static constexpr int BB = 16;
static constexpr int NN = 325;
static constexpr int DD = 64;
static constexpr int HH = 4;
static constexpr int DHH = 16;
static constexpr int SEQ = 12;
static constexpr int MAXDEG = 128;
static constexpr int BN = BB * NN;
static constexpr float DT = 0.1f;
static constexpr float NEG = 0.2f;
static constexpr float THRESH = 0.9f;

// 64x64 matvec: out[lane] = sum_d x[d] * M[d][lane]; x broadcast via per-wave LDS row.
__device__ __forceinline__ float matvec64(const float* __restrict__ sM, float* xrow,
                                          float xval, int lane) {
  xrow[lane] = xval;
  __threadfence_block();  // wave-level LDS RAW ordering
  float s0 = 0.f, s1 = 0.f, s2 = 0.f, s3 = 0.f;
#pragma unroll
  for (int d = 0; d < 64; d += 4) {
    s0 = fmaf(xrow[d + 0], sM[(d + 0) * 64 + lane], s0);
    s1 = fmaf(xrow[d + 1], sM[(d + 1) * 64 + lane], s1);
    s2 = fmaf(xrow[d + 2], sM[(d + 2) * 64 + lane], s2);
    s3 = fmaf(xrow[d + 3], sM[(d + 3) * 64 + lane], s3);
  }
  __threadfence_block();  // protect WAR before xrow reuse
  return (s0 + s1) + (s2 + s3);
}

// es/ed for node n from its fresh h value (lane = head*16+hd). Reduce within 16-lane head group.
__device__ __forceinline__ void write_esed(float hval, const float* __restrict__ sa,
                                           const float* __restrict__ sd,
                                           float* __restrict__ es, float* __restrict__ ed,
                                           int n, int head, int hd) {
  float p = hval * sa[head * DHH + hd];
  float q = hval * sd[head * DHH + hd];
#pragma unroll
  for (int mm = 1; mm < 16; mm <<= 1) {
    p += __shfl_xor(p, mm, 64);
    q += __shfl_xor(q, mm, 64);
  }
  if (hd == 0) {
    es[n * HH + head] = p;
    ed[n * HH + head] = q;
  }
}

// Sparse masked-softmax attention for node (b,i): returns out channel `lane`.
__device__ __forceinline__ float attn(const float* __restrict__ hbuf,
                                      const float* __restrict__ es,
                                      const float* __restrict__ ed,
                                      const int* __restrict__ deg,
                                      const int* __restrict__ cols,
                                      int b, int i, int lane, int head, int hd) {
  const float esi = es[(b * NN + i) * HH + head];
  const int dg = deg[i];
  const int* __restrict__ cl = cols + i * MAXDEG;
  const float* __restrict__ edb = ed + (size_t)b * NN * HH + head;
  const float* __restrict__ hbb = hbuf + (size_t)b * NN * DD + lane;
  // pass 1: row max (neighbors strided over the 16 lanes of this head group)
  float m = -1e30f;
  for (int q = hd; q < dg; q += 16) {
    int j = cl[q];
    float e = esi + edb[j * HH];
    e = fmaxf(e, NEG * e);  // leaky_relu
    m = fmaxf(m, e);
  }
#pragma unroll
  for (int mm = 1; mm < 16; mm <<= 1) m = fmaxf(m, __shfl_xor(m, mm, 64));
  // pass 2: accumulate
  float av = 0.f, den = 0.f;
  for (int q = 0; q < dg; ++q) {
    int j = cl[q];
    float e = esi + edb[j * HH];
    e = fmaxf(e, NEG * e);
    float w = __expf(e - m);
    den += w;
    av = fmaf(w, hbb[(size_t)j * DD], av);
  }
  return av / den;
}

__global__ __launch_bounds__(512) void ode_kernel(
    const float* __restrict__ y0, const float* __restrict__ graph,
    const float* __restrict__ Wg, const float* __restrict__ a_src,
    const float* __restrict__ a_dst, const float* __restrict__ W1,
    const float* __restrict__ b1, const float* __restrict__ W2,
    const float* __restrict__ b2, float* __restrict__ out,
    int* __restrict__ deg, int* __restrict__ cols,
    float* __restrict__ ha, float* __restrict__ hb,
    float* __restrict__ es0, float* __restrict__ ed0,
    float* __restrict__ es1, float* __restrict__ ed1,
    float* __restrict__ yy, float* __restrict__ acc) {
  __shared__ float sW[2][64 * 64];   // GAT layer weights
  __shared__ float sWh[64 * 64];     // head W1
  __shared__ float sasrc[2][HH * DHH], sadst[2][HH * DHH];
  __shared__ float sb1[64], sW2[64];
  __shared__ float xbuf[8][64];      // per-wave broadcast row (8 waves/block)

  const int tid = threadIdx.x;
  const int lane = tid & 63;
  const int wv = tid >> 6;
  const int gwave = blockIdx.x * (blockDim.x >> 6) + wv;
  const int total_waves = (gridDim.x * blockDim.x) >> 6;
  const int head = lane >> 4;
  const int hd = lane & 15;
  const float b2v = b2[0];

  // stage weights into LDS
  for (int idx = tid; idx < 64 * 64; idx += blockDim.x) {
    sW[0][idx] = Wg[idx];
    sW[1][idx] = Wg[64 * 64 + idx];
    sWh[idx] = W1[idx];
  }
  if (tid < 64) {
    sb1[tid] = b1[tid];
    sW2[tid] = W2[tid];
  }
  if (tid < 2 * HH * DHH) {
    int l = tid / (HH * DHH), r = tid % (HH * DHH);
    sasrc[l][r] = a_src[tid];
    sadst[l][r] = a_dst[tid];
  }
  __syncthreads();

  cg::grid_group grid = cg::this_grid();

  // ---- setup phase: adjacency (wave-ballot compaction), y init, h0, es/ed, head out t=0
  for (int i = gwave; i < NN; i += total_waves) {
    int dcount = 0;
    for (int base = 0; base < NN; base += 64) {
      int j = base + lane;
      bool pred = (j < NN) && ((graph[i * NN + j] > THRESH) || (j == i));
      unsigned long long mask = __ballot(pred);
      int pos = dcount + (int)__popcll(mask & ((1ULL << lane) - 1ULL));
      if (pred) cols[i * MAXDEG + pos] = j;
      dcount += (int)__popcll(mask);
    }
    if (lane == 0) deg[i] = dcount;
  }
  for (int n = gwave; n < BN; n += total_waves) {
    int b = n / NN, i = n % NN;
    float yv = y0[(size_t)n * DD + lane];
    yy[(size_t)n * DD + lane] = yv;
    float h1 = matvec64(sW[0], xbuf[wv], yv, lane);
    ha[(size_t)n * DD + lane] = h1;
    write_esed(h1, sasrc[0], sadst[0], es0, ed0, n, head, hd);
    // head output for t = 0
    float z = tanhf(matvec64(sWh, xbuf[wv], yv, lane) + sb1[lane]);
    float o = z * sW2[lane];
#pragma unroll
    for (int mm = 1; mm < 64; mm <<= 1) o += __shfl_xor(o, mm, 64);
    if (lane == 0) out[((size_t)b * (SEQ + 1) + 0) * NN + i] = o + b2v;
  }
  __threadfence();
  grid.sync();
  __threadfence();

  // ---- main loop: 12 steps x 4 stages x 2 layers, one grid sync per layer eval
  for (int t = 0; t < SEQ; ++t) {
    for (int s = 0; s < 4; ++s) {
      // phase A: GAT layer 0 attention -> ELU -> GEMM W1 -> hb, es1/ed1
      for (int n = gwave; n < BN; n += total_waves) {
        int b = n / NN, i = n % NN;
        float x = attn(ha, es0, ed0, deg, cols, b, i, lane, head, hd);
        x = x > 0.f ? x : __expf(x) - 1.f;  // elu between layers
        float h2 = matvec64(sW[1], xbuf[wv], x, lane);
        hb[(size_t)n * DD + lane] = h2;
        write_esed(h2, sasrc[1], sadst[1], es1, ed1, n, head, hd);
      }
      __threadfence();
      grid.sync();
      __threadfence();

      // phase B: GAT layer 1 attention -> k -> RK4 update -> GEMM W0 -> ha, es0/ed0
      for (int n = gwave; n < BN; n += total_waves) {
        int b = n / NN, i = n % NN;
        float k = attn(hb, es1, ed1, deg, cols, b, i, lane, head, hd);
        size_t idx = (size_t)n * DD + lane;
        float yv = yy[idx];
        float xn;
        if (s == 0) {
          acc[idx] = k;
          xn = yv + 0.5f * DT * k;
        } else if (s == 1) {
          acc[idx] += 2.f * k;
          xn = yv + 0.5f * DT * k;
        } else if (s == 2) {
          acc[idx] += 2.f * k;
          xn = yv + DT * k;
        } else {
          float a4 = acc[idx] + k;
          float ynew = yv + (DT / 6.f) * a4;
          yy[idx] = ynew;
          // head output for t+1
          float z = tanhf(matvec64(sWh, xbuf[wv], ynew, lane) + sb1[lane]);
          float o = z * sW2[lane];
#pragma unroll
          for (int mm = 1; mm < 64; mm <<= 1) o += __shfl_xor(o, mm, 64);
          if (lane == 0) out[((size_t)b * (SEQ + 1) + (t + 1)) * NN + i] = o + b2v;
          xn = ynew;
        }
        float h1 = matvec64(sW[0], xbuf[wv], xn, lane);
        ha[idx] = h1;
        write_esed(h1, sasrc[0], sadst[0], es0, ed0, n, head, hd);
      }
      __threadfence();
      grid.sync();
      __threadfence();
    }
  }
}

extern "C" void kernel_launch(void* const* d_in, const int* in_sizes, int n_in,
                              void* d_out, int out_size, void* d_ws, size_t ws_size,
                              hipStream_t stream) {
  const float* y0 = (const float*)d_in[0];
  const float* graph = (const float*)d_in[1];
  const float* Wg = (const float*)d_in[2];
  const float* a_src = (const float*)d_in[3];
  const float* a_dst = (const float*)d_in[4];
  const float* W1 = (const float*)d_in[5];
  const float* b1 = (const float*)d_in[6];
  const float* W2 = (const float*)d_in[7];
  const float* b2 = (const float*)d_in[8];
  float* out = (float*)d_out;

  char* ws = (char*)d_ws;
  size_t off = 0;
  auto take = [&](size_t bytes) -> char* {
    char* p = ws + off;
    off += (bytes + 255) & ~size_t(255);
    return p;
  };
  int* deg = (int*)take(NN * sizeof(int));
  int* cols = (int*)take((size_t)NN * MAXDEG * sizeof(int));
  float* ha = (float*)take((size_t)BN * DD * sizeof(float));
  float* hb = (float*)take((size_t)BN * DD * sizeof(float));
  float* es0 = (float*)take((size_t)BN * HH * sizeof(float));
  float* ed0 = (float*)take((size_t)BN * HH * sizeof(float));
  float* es1 = (float*)take((size_t)BN * HH * sizeof(float));
  float* ed1 = (float*)take((size_t)BN * HH * sizeof(float));
  float* yy = (float*)take((size_t)BN * DD * sizeof(float));
  float* acc = (float*)take((size_t)BN * DD * sizeof(float));
  if (off > ws_size) return;  // insufficient workspace: leave output poisoned (loud failure)

  void* args[] = {&y0, &graph, &Wg, &a_src, &a_dst, &W1, &b1, &W2, &b2, &out,
                  &deg, &cols, &ha, &hb, &es0, &ed0, &es1, &ed1, &yy, &acc};
  hipLaunchCooperativeKernel((void*)ode_kernel, dim3(256), dim3(512), args, 0, stream);
}